// Round 1
// baseline (2900.578 us; speedup 1.0000x reference)
//
#include <hip/hip_runtime.h>
#include <math.h>

// Shapes: B=32, S=32, D=64, E=768
// out layout (floats): [0,32) agg | [32,1056) target_instance | [1056,2080) pred
//                      | [2080,2112) num_seg (as float) | [2112] cos_prior

__device__ __forceinline__ float gelu_f(float x) {
    return 0.5f * x * (1.0f + erff(x * 0.70710678118654752440f));
}
__device__ __forceinline__ float wave_sum(float v) {
    for (int o = 32; o; o >>= 1) v += __shfl_xor(v, o);
    return v;
}
__device__ __forceinline__ float wave_max(float v) {
    for (int o = 32; o; o >>= 1) v = fmaxf(v, __shfl_xor(v, o));
    return v;
}

__global__ __launch_bounds__(1024) void prep_out(const float* __restrict__ agg,
                                                 const float* __restrict__ tinst,
                                                 const int* __restrict__ nseg,
                                                 float* __restrict__ out) {
    int t = threadIdx.x;           // 0..1023
    int b = t >> 5, s = t & 31;
    out[32 + t] = (s < nseg[b]) ? tinst[t] : 1.0f;
    if (t < 32) {
        out[t] = agg[t];
        out[2080 + t] = (float)nseg[t];
    }
}

// inverse L2 norms for the cosine branch: rows 0..2047 = doc[b,d], 2048..3071 = sum[b,s]
__global__ __launch_bounds__(256) void rnorm_k(const float* __restrict__ doc,
                                               const float* __restrict__ sume,
                                               float* __restrict__ rnd,
                                               float* __restrict__ rns) {
    int lane = threadIdx.x & 63, w = threadIdx.x >> 6;
    int row = blockIdx.x * 4 + w;
    const float* p; float* dst;
    if (row < 2048) { p = doc + row * 768; dst = rnd + row; }
    else            { p = sume + (row - 2048) * 768; dst = rns + (row - 2048); }
    float s = 0.f;
    #pragma unroll
    for (int m = 0; m < 12; ++m) { float v = p[lane + 64 * m]; s += v * v; }
    s = wave_sum(s);
    if (lane == 0) *dst = rsqrtf(fmaxf(s, 1e-12f));
}

// hd[3072 rows? no: 2048][768] = doc@W1[:768];  hs[1024][768] = sum@W1[768:]
// combined row space: 0..2047 doc, 2048..3071 sum.  64x64 tile, thread 4x4.
__global__ __launch_bounds__(256) void gemm_w1(const float* __restrict__ doc,
                                               const float* __restrict__ sume,
                                               const float* __restrict__ W1,
                                               float* __restrict__ hd,
                                               float* __restrict__ hs) {
    __shared__ float As[16][65];
    __shared__ float Bs[16][65];
    int row0 = blockIdx.y * 64;
    int col0 = blockIdx.x * 64;
    const float* A; const float* Bm; float* O; int arow;
    if (row0 < 2048) { A = doc;  Bm = W1;             O = hd; arow = row0; }
    else             { A = sume; Bm = W1 + 768 * 768; O = hs; arow = row0 - 2048; }
    int tid = threadIdx.x;
    int tx = tid & 15, ty = tid >> 4;
    float acc[4][4] = {};
    for (int kt = 0; kt < 768; kt += 16) {
        #pragma unroll
        for (int j = 0; j < 4; ++j) {
            int idx = tid + 256 * j;
            int kk = idx & 15, m = idx >> 4;
            As[kk][m] = A[(arow + m) * 768 + kt + kk];
            int cc = idx & 63, k2 = idx >> 6;
            Bs[k2][cc] = Bm[(kt + k2) * 768 + col0 + cc];
        }
        __syncthreads();
        #pragma unroll
        for (int kk = 0; kk < 16; ++kk) {
            float a[4], bb[4];
            #pragma unroll
            for (int i = 0; i < 4; ++i) a[i] = As[kk][ty * 4 + i];
            #pragma unroll
            for (int j = 0; j < 4; ++j) bb[j] = Bs[kk][tx + 16 * j];
            #pragma unroll
            for (int i = 0; i < 4; ++i)
                #pragma unroll
                for (int j = 0; j < 4; ++j) acc[i][j] += a[i] * bb[j];
        }
        __syncthreads();
    }
    #pragma unroll
    for (int i = 0; i < 4; ++i)
        #pragma unroll
        for (int j = 0; j < 4; ++j)
            O[(arow + ty * 4 + i) * 768 + col0 + tx + 16 * j] = acc[i][j];
}

// One block per (b,s). 256 threads = 4 waves. Computes score[b,s,d] for d=0..63,
// seg_max -> pred, cosine dscos, per-(b,s) diff contribution.
__global__ __launch_bounds__(256) void fused_score(
    const float* __restrict__ hd, const float* __restrict__ hs,
    const float* __restrict__ doc, const float* __restrict__ sume,
    const float* __restrict__ b1, const float* __restrict__ W2,
    const float* __restrict__ b2, const float* __restrict__ W3,
    const float* __restrict__ b3, const int* __restrict__ ndoc,
    const int* __restrict__ nseg, const float* __restrict__ rnd,
    const float* __restrict__ rns, float* __restrict__ out,
    float* __restrict__ diffc)
{
    int bs = blockIdx.x;
    int b = bs >> 5, s = bs & 31;
    int tid = threadIdx.x;
    int c = tid & 63, rg = tid >> 6;   // lane, wave id
    __shared__ float hsb[768];         // h_seg row + b1 (later reused for raw sum row)
    __shared__ float h1t[16][768];     // gelu'd A-tile (16 d-rows)
    __shared__ float w2t[16][384];     // W2 k-tile
    __shared__ float scores[64];
    __shared__ float rowred[4];
    __shared__ float predsh;
    int nd = ndoc[b], ns = nseg[b];

    for (int j = tid; j < 768; j += 256) hsb[j] = hs[bs * 768 + j] + b1[j];
    __syncthreads();

    for (int dt = 0; dt < 4; ++dt) {
        int d0 = dt * 16;
        // build h1 tile: h1[r][k] = gelu(hd[b, d0+r, k] + hs[b,s,k] + b1[k])
        for (int r = 0; r < 16; ++r) {
            const float* hdr = hd + (b * 64 + d0 + r) * 768;
            #pragma unroll
            for (int j = 0; j < 3; ++j) {
                int k = tid + 256 * j;
                h1t[r][k] = gelu_f(hdr[k] + hsb[k]);
            }
        }
        __syncthreads();

        float acc[4][6];
        #pragma unroll
        for (int i = 0; i < 4; ++i)
            #pragma unroll
            for (int j = 0; j < 6; ++j) acc[i][j] = 0.f;

        for (int kt = 0; kt < 768; kt += 16) {
            #pragma unroll
            for (int j = 0; j < 24; ++j) {
                int idx = tid + 256 * j;                  // 0..6143
                int rr = idx / 384, cc = idx - rr * 384;
                w2t[rr][cc] = W2[(kt + rr) * 384 + cc];
            }
            __syncthreads();
            #pragma unroll
            for (int kk = 0; kk < 16; ++kk) {
                float a0 = h1t[rg][kt + kk];
                float a1 = h1t[rg + 4][kt + kk];
                float a2 = h1t[rg + 8][kt + kk];
                float a3 = h1t[rg + 12][kt + kk];
                #pragma unroll
                for (int j = 0; j < 6; ++j) {
                    float bb = w2t[kk][c + 64 * j];
                    acc[0][j] += a0 * bb;
                    acc[1][j] += a1 * bb;
                    acc[2][j] += a2 * bb;
                    acc[3][j] += a3 * bb;
                }
            }
            __syncthreads();
        }

        // h2 = gelu(acc + b2); score_pre = h2 . W3 ; wave-reduce over the 64 col-lanes
        float partial[4] = {0.f, 0.f, 0.f, 0.f};
        #pragma unroll
        for (int j = 0; j < 6; ++j) {
            int cc = c + 64 * j;
            float w3 = W3[cc], bb2 = b2[cc];
            #pragma unroll
            for (int i = 0; i < 4; ++i)
                partial[i] += gelu_f(acc[i][j] + bb2) * w3;
        }
        float bb3 = b3[0];
        #pragma unroll
        for (int i = 0; i < 4; ++i) {
            float p = wave_sum(partial[i]);
            if (c == 0) scores[d0 + rg + 4 * i] = 1.f / (1.f + expf(-(p + bb3)));
        }
        __syncthreads();
    }

    // seg_max over d < nd (scores > 0 so zero-fill is equivalent to the masked max)
    if (rg == 0) {
        float v = (c < nd) ? scores[c] : 0.f;
        v = wave_max(v);
        if (c == 0) {
            float segw = (ns > 10) ? 1.f : 100.f;
            float pred = segw * v;
            out[1056 + bs] = pred;
            predsh = pred;
        }
    }
    __syncthreads();

    // cosine branch: dscos = max_{d<nd} (1 - dot(dn_d, sn_s))/2
    for (int j = tid; j < 768; j += 256) hsb[j] = sume[bs * 768 + j];
    __syncthreads();
    float rs = rns[bs];
    float mymax = 0.f;
    for (int i = 0; i < 16; ++i) {
        int d = rg * 16 + i;
        const float* dr = doc + (b * 64 + d) * 768;
        float dot = 0.f;
        #pragma unroll
        for (int m = 0; m < 12; ++m) dot += dr[c + 64 * m] * hsb[c + 64 * m];
        dot = wave_sum(dot);
        if (d < nd) {
            float val = (1.f - dot * rnd[b * 64 + d] * rs) * 0.5f;
            mymax = fmaxf(mymax, val);
        }
    }
    if (c == 0) rowred[rg] = mymax;
    __syncthreads();
    if (tid == 0) {
        float dscos = fmaxf(fmaxf(rowred[0], rowred[1]), fmaxf(rowred[2], rowred[3]));
        float diff = (s < ns) ? fabsf(dscos - predsh) / (float)ns : 0.f;
        diffc[bs] = diff;
    }
}

__global__ __launch_bounds__(1024) void finish_k(const float* __restrict__ diffc,
                                                 float* __restrict__ out) {
    __shared__ float red[16];
    int t = threadIdx.x, lane = t & 63, w = t >> 6;
    float v = diffc[t];
    v = wave_sum(v);
    if (lane == 0) red[w] = v;
    __syncthreads();
    if (w == 0) {
        float x = (lane < 16) ? red[lane] : 0.f;
        x = wave_sum(x);
        if (lane == 0) out[2112] = x * (1.f / 32.f);
    }
}

extern "C" void kernel_launch(void* const* d_in, const int* in_sizes, int n_in,
                              void* d_out, int out_size, void* d_ws, size_t ws_size,
                              hipStream_t stream) {
    const float* doc   = (const float*)d_in[0];   // [32,64,768]
    const float* sume  = (const float*)d_in[1];   // [32,32,768]
    const int*   ndoc  = (const int*)d_in[2];     // [32]
    const int*   nseg  = (const int*)d_in[3];     // [32]
    const float* agg   = (const float*)d_in[4];   // [32]
    const float* tinst = (const float*)d_in[5];   // [32,32]
    const float* W1    = (const float*)d_in[6];   // [1536,768]
    const float* b1    = (const float*)d_in[7];   // [768]
    const float* W2    = (const float*)d_in[8];   // [768,384]
    const float* b2    = (const float*)d_in[9];   // [384]
    const float* W3    = (const float*)d_in[10];  // [384,1]
    const float* b3    = (const float*)d_in[11];  // [1]
    float* out = (float*)d_out;
    float* ws  = (float*)d_ws;

    float* hd    = ws;                    // 2048*768
    float* hs    = hd + 2048 * 768;       // 1024*768
    float* rnd   = hs + 1024 * 768;       // 2048
    float* rns   = rnd + 2048;            // 1024
    float* diffc = rns + 1024;            // 1024

    prep_out<<<1, 1024, 0, stream>>>(agg, tinst, nseg, out);
    rnorm_k<<<768, 256, 0, stream>>>(doc, sume, rnd, rns);
    gemm_w1<<<dim3(12, 48), 256, 0, stream>>>(doc, sume, W1, hd, hs);
    fused_score<<<1024, 256, 0, stream>>>(hd, hs, doc, sume, b1, W2, b2, W3, b3,
                                          ndoc, nseg, rnd, rns, out, diffc);
    finish_k<<<1, 1024, 0, stream>>>(diffc, out);
}

// Round 2
// 172.333 us; speedup vs baseline: 16.8312x; 16.8312x over previous
//
#include <hip/hip_runtime.h>
#include <math.h>

// Shapes: B=32, S=32, D=64, E=768
// out layout (floats): [0,32) agg | [32,1056) target_instance | [1056,2080) pred
//                      | [2080,2112) num_seg (as float) | [2112] cos_prior

typedef __bf16 bf16x8 __attribute__((ext_vector_type(8)));
typedef float f32x4 __attribute__((ext_vector_type(4)));

__device__ __forceinline__ float gelu_f(float x) {
    return 0.5f * x * (1.0f + erff(x * 0.70710678118654752440f));
}
__device__ __forceinline__ unsigned short f2bf(float x) {
    unsigned int u = __float_as_uint(x);
    u = (u + 0x7fffu + ((u >> 16) & 1u)) >> 16;
    return (unsigned short)u;
}
__device__ __forceinline__ float wave_sum(float v) {
    for (int o = 32; o; o >>= 1) v += __shfl_xor(v, o);
    return v;
}
__device__ __forceinline__ float wave_max(float v) {
    for (int o = 32; o; o >>= 1) v = fmaxf(v, __shfl_xor(v, o));
    return v;
}

__global__ __launch_bounds__(1024) void prep_out(const float* __restrict__ agg,
                                                 const float* __restrict__ tinst,
                                                 const int* __restrict__ nseg,
                                                 float* __restrict__ out) {
    int t = threadIdx.x;
    int b = t >> 5, s = t & 31;
    out[32 + t] = (s < nseg[b]) ? tinst[t] : 1.0f;
    if (t < 32) {
        out[t] = agg[t];
        out[2080 + t] = (float)nseg[t];
    }
}

// convert doc+sum embeddings to bf16 (vectorized float4 -> 4x bf16)
__global__ __launch_bounds__(256) void cvt_emb(const float* __restrict__ doc,
                                               const float* __restrict__ sume,
                                               unsigned short* __restrict__ docbf,
                                               unsigned short* __restrict__ sumbf) {
    const int N0q = (2048 * 768) / 4;   // doc quads
    int i4 = blockIdx.x * 256 + threadIdx.x;   // 0 .. 589823
    const float4* src; ushort4* dst; int idx;
    if (i4 < N0q) { src = (const float4*)doc;  dst = (ushort4*)docbf; idx = i4; }
    else          { src = (const float4*)sume; dst = (ushort4*)sumbf; idx = i4 - N0q; }
    float4 v = src[idx];
    ushort4 o;
    o.x = f2bf(v.x); o.y = f2bf(v.y); o.z = f2bf(v.z); o.w = f2bf(v.w);
    dst[idx] = o;
}

// transpose + convert: in[R][C] fp32 -> out[C][R] bf16
__global__ __launch_bounds__(256) void tr_cvt(const float* __restrict__ in,
                                              unsigned short* __restrict__ out,
                                              int R, int C) {
    __shared__ float tile[64][65];
    int t = threadIdx.x;
    int r0 = blockIdx.y * 64, c0 = blockIdx.x * 64;
    #pragma unroll
    for (int p = 0; p < 16; ++p) {
        int r = p * 4 + (t >> 6), c = t & 63;
        tile[r][c] = in[(r0 + r) * C + c0 + c];
    }
    __syncthreads();
    #pragma unroll
    for (int p = 0; p < 16; ++p) {
        int cc = p * 4 + (t >> 6), rr = t & 63;
        out[(c0 + cc) * R + r0 + rr] = f2bf(tile[rr][cc]);
    }
}

// inverse L2 norms: rows 0..2047 doc, 2048..3071 sum
__global__ __launch_bounds__(256) void rnorm_k(const float* __restrict__ doc,
                                               const float* __restrict__ sume,
                                               float* __restrict__ rnd,
                                               float* __restrict__ rns) {
    int lane = threadIdx.x & 63, w = threadIdx.x >> 6;
    int row = blockIdx.x * 4 + w;
    const float* p; float* dst;
    if (row < 2048) { p = doc + row * 768; dst = rnd + row; }
    else            { p = sume + (row - 2048) * 768; dst = rns + (row - 2048); }
    float s = 0.f;
    #pragma unroll
    for (int m = 0; m < 12; ++m) { float v = p[lane + 64 * m]; s += v * v; }
    s = wave_sum(s);
    if (lane == 0) *dst = rsqrtf(fmaxf(s, 1e-12f));
}

// MFMA GEMM stage 1: rows 0..2047 = docbf @ W1a, rows 2048..3071 = sumbf @ W1b.
// W1t is [768 out][1536 k'] bf16 with k' = (half*768 + k). Output fp32 hd/hs.
// 128x128 tile, 256 threads (4 waves 2x2), BK=64.
__global__ __launch_bounds__(256) void gemm1(const unsigned short* __restrict__ docbf,
                                             const unsigned short* __restrict__ sumbf,
                                             const unsigned short* __restrict__ W1t,
                                             float* __restrict__ hd,
                                             float* __restrict__ hs) {
    __shared__ __align__(16) unsigned short Asw[128 * 64];
    __shared__ __align__(16) unsigned short Bsw[128 * 64];
    int t = threadIdx.x;
    int row0 = blockIdx.y * 128, col0 = blockIdx.x * 128;
    bool is_doc = row0 < 2048;
    const unsigned short* A = is_doc ? (docbf + row0 * 768) : (sumbf + (row0 - 2048) * 768);
    int kbase = is_doc ? 0 : 768;
    float* O = is_doc ? (hd + row0 * 768) : (hs + (row0 - 2048) * 768);

    int l = t & 63, w = t >> 6;
    int wr = w >> 1, wc = w & 1;
    f32x4 acc[4][4];
    #pragma unroll
    for (int i = 0; i < 4; ++i)
        #pragma unroll
        for (int j = 0; j < 4; ++j) acc[i][j] = (f32x4)0.f;

    char* AswB = (char*)Asw;
    char* BswB = (char*)Bsw;
    for (int kt = 0; kt < 768; kt += 64) {
        __syncthreads();
        #pragma unroll
        for (int p = 0; p < 4; ++p) {
            int r = p * 32 + (t >> 3);
            int ko = (t & 7) * 8;
            bf16x8 av = *(const bf16x8*)(A + r * 768 + kt + ko);
            int byte = (r * 128 + ko * 2) ^ ((r & 7) << 4);
            *(bf16x8*)(AswB + byte) = av;
            bf16x8 bv = *(const bf16x8*)(W1t + (col0 + r) * 1536 + kbase + kt + ko);
            *(bf16x8*)(BswB + byte) = bv;
        }
        __syncthreads();
        #pragma unroll
        for (int ks = 0; ks < 2; ++ks) {
            int koff = (ks * 32 + (l >> 4) * 8) * 2;
            bf16x8 af[4], bf[4];
            #pragma unroll
            for (int fr = 0; fr < 4; ++fr) {
                int r = wr * 64 + fr * 16 + (l & 15);
                af[fr] = *(const bf16x8*)(AswB + ((r * 128 + koff) ^ ((r & 7) << 4)));
            }
            #pragma unroll
            for (int fc = 0; fc < 4; ++fc) {
                int n = wc * 64 + fc * 16 + (l & 15);
                bf[fc] = *(const bf16x8*)(BswB + ((n * 128 + koff) ^ ((n & 7) << 4)));
            }
            #pragma unroll
            for (int fr = 0; fr < 4; ++fr)
                #pragma unroll
                for (int fc = 0; fc < 4; ++fc)
                    acc[fr][fc] = __builtin_amdgcn_mfma_f32_16x16x32_bf16(af[fr], bf[fc], acc[fr][fc], 0, 0, 0);
        }
    }
    #pragma unroll
    for (int fr = 0; fr < 4; ++fr)
        #pragma unroll
        for (int fc = 0; fc < 4; ++fc)
            #pragma unroll
            for (int j = 0; j < 4; ++j) {
                int r = wr * 64 + fr * 16 + (l >> 4) * 4 + j;
                int c = col0 + wc * 64 + fc * 16 + (l & 15);
                O[r * 768 + c] = acc[fr][fc][j];
            }
}

// Main fused kernel: one block per (b, s-pair). 512 threads = 8 waves (2 row x 4 col).
// Rows: r = sl*64 + d (128 rows), cols: 384 (full W2 output width).
// A[r][k] = gelu(hd[b,d,k] + hs[b,s0+sl,k] + b1[k]) built on the fly -> bf16 LDS.
__global__ __launch_bounds__(512) void score_mfma(
    const float* __restrict__ hd, const float* __restrict__ hs,
    const float* __restrict__ b1, const unsigned short* __restrict__ W2t,
    const float* __restrict__ b2, const float* __restrict__ W3,
    const float* __restrict__ b3, const int* __restrict__ ndoc,
    const int* __restrict__ nseg, float* __restrict__ out)
{
    __shared__ __align__(16) unsigned short Asw[128 * 64];   // 16 KB
    __shared__ __align__(16) unsigned short Bsw[384 * 64];   // 48 KB
    __shared__ float spart[4][128];

    int t = threadIdx.x;
    int b = blockIdx.x >> 4, sp = blockIdx.x & 15;
    int s0 = sp * 2;
    int l = t & 63, w = t >> 6;
    int wr = w >> 2, wc = w & 3;                 // 2 x 4 waves
    int nd = ndoc[b], ns = nseg[b];

    f32x4 acc[4][6];
    #pragma unroll
    for (int i = 0; i < 4; ++i)
        #pragma unroll
        for (int j = 0; j < 6; ++j) acc[i][j] = (f32x4)0.f;

    char* AswB = (char*)Asw;
    char* BswB = (char*)Bsw;
    const float* hdB = hd + b * 64 * 768;
    const float* hs0 = hs + (b * 32 + s0) * 768;
    const float* hs1 = hs0 + 768;
    int k0 = (t & 31) * 2;                        // thread's fixed k-pair within BK=64

    for (int kt = 0; kt < 768; kt += 64) {
        __syncthreads();
        // per-thread invariants for this K-tile
        float2 ha = *(const float2*)(hs0 + kt + k0);
        float2 hb = *(const float2*)(hs1 + kt + k0);
        float2 bv = *(const float2*)(b1 + kt + k0);
        ha.x += bv.x; ha.y += bv.y; hb.x += bv.x; hb.y += bv.y;
        // build A tile: 8 passes x 16 rows
        #pragma unroll
        for (int p = 0; p < 8; ++p) {
            int r = p * 16 + (t >> 5);
            int d = r & 63, sl = r >> 6;
            float2 hv = *(const float2*)(hdB + d * 768 + kt + k0);
            float x0 = hv.x + (sl ? hb.x : ha.x);
            float x1 = hv.y + (sl ? hb.y : ha.y);
            unsigned int packed = (unsigned int)f2bf(gelu_f(x0)) |
                                  ((unsigned int)f2bf(gelu_f(x1)) << 16);
            int byte = (r * 128 + k0 * 2) ^ ((r & 7) << 4);
            *(unsigned int*)(AswB + byte) = packed;
        }
        // stage W2t tile: 6 passes x 64 rows
        #pragma unroll
        for (int q = 0; q < 6; ++q) {
            int n = q * 64 + (t >> 3);
            int ko = (t & 7) * 8;
            bf16x8 bvv = *(const bf16x8*)(W2t + n * 768 + kt + ko);
            int byte = (n * 128 + ko * 2) ^ ((n & 7) << 4);
            *(bf16x8*)(BswB + byte) = bvv;
        }
        __syncthreads();
        #pragma unroll
        for (int ks = 0; ks < 2; ++ks) {
            int koff = (ks * 32 + (l >> 4) * 8) * 2;
            bf16x8 af[4], bf[6];
            #pragma unroll
            for (int fr = 0; fr < 4; ++fr) {
                int r = wr * 64 + fr * 16 + (l & 15);
                af[fr] = *(const bf16x8*)(AswB + ((r * 128 + koff) ^ ((r & 7) << 4)));
            }
            #pragma unroll
            for (int fc = 0; fc < 6; ++fc) {
                int n = wc * 96 + fc * 16 + (l & 15);
                bf[fc] = *(const bf16x8*)(BswB + ((n * 128 + koff) ^ ((n & 7) << 4)));
            }
            #pragma unroll
            for (int fr = 0; fr < 4; ++fr)
                #pragma unroll
                for (int fc = 0; fc < 6; ++fc)
                    acc[fr][fc] = __builtin_amdgcn_mfma_f32_16x16x32_bf16(af[fr], bf[fc], acc[fr][fc], 0, 0, 0);
        }
    }

    // epilogue: h2 = gelu(acc + b2); partial score = h2 . W3 over this wave's 96 cols
    float b2v[6], w3v[6];
    #pragma unroll
    for (int fc = 0; fc < 6; ++fc) {
        int col = wc * 96 + fc * 16 + (l & 15);
        b2v[fc] = b2[col];
        w3v[fc] = W3[col];
    }
    #pragma unroll
    for (int fr = 0; fr < 4; ++fr) {
        #pragma unroll
        for (int j = 0; j < 4; ++j) {
            float pr = 0.f;
            #pragma unroll
            for (int fc = 0; fc < 6; ++fc)
                pr += gelu_f(acc[fr][fc][j] + b2v[fc]) * w3v[fc];
            pr += __shfl_xor(pr, 1);
            pr += __shfl_xor(pr, 2);
            pr += __shfl_xor(pr, 4);
            pr += __shfl_xor(pr, 8);
            if ((l & 15) == 0)
                spart[wc][wr * 64 + fr * 16 + (l >> 4) * 4 + j] = pr;
        }
    }
    __syncthreads();
    if (t < 128) {
        int row = t;
        float v = spart[0][row] + spart[1][row] + spart[2][row] + spart[3][row] + b3[0];
        float sc = 1.f / (1.f + expf(-v));
        int d = row & 63, sl = row >> 6;
        float m = (d < nd) ? sc : 0.f;
        m = wave_max(m);
        if ((t & 63) == 0) {
            float segw = (ns > 10) ? 1.f : 100.f;
            out[1056 + b * 32 + s0 + sl] = segw * m;
        }
    }
}

// cosine branch: dscos = max_{d<nd} (1 - cos)/2 ; diff contribution per (b,s)
__global__ __launch_bounds__(256) void cos_diff(const float* __restrict__ doc,
                                                const float* __restrict__ sume,
                                                const int* __restrict__ ndoc,
                                                const int* __restrict__ nseg,
                                                const float* __restrict__ rnd,
                                                const float* __restrict__ rns,
                                                const float* __restrict__ out,
                                                float* __restrict__ diffc) {
    __shared__ float srow[768];
    __shared__ float rowred[4];
    int bs = blockIdx.x;
    int b = bs >> 5, s = bs & 31;
    int t = threadIdx.x;
    int c = t & 63, rg = t >> 6;
    int nd = ndoc[b], ns = nseg[b];
    for (int j = t; j < 768; j += 256) srow[j] = sume[bs * 768 + j];
    __syncthreads();
    float rs = rns[bs];
    float mymax = 0.f;
    for (int i = 0; i < 16; ++i) {
        int d = rg * 16 + i;
        const float* dr = doc + (b * 64 + d) * 768;
        float dot = 0.f;
        #pragma unroll
        for (int m = 0; m < 12; ++m) dot += dr[c + 64 * m] * srow[c + 64 * m];
        dot = wave_sum(dot);
        if (d < nd) {
            float val = (1.f - dot * rnd[b * 64 + d] * rs) * 0.5f;
            mymax = fmaxf(mymax, val);
        }
    }
    if (c == 0) rowred[rg] = mymax;
    __syncthreads();
    if (t == 0) {
        float dscos = fmaxf(fmaxf(rowred[0], rowred[1]), fmaxf(rowred[2], rowred[3]));
        float pred = out[1056 + bs];
        diffc[bs] = (s < ns) ? fabsf(dscos - pred) / (float)ns : 0.f;
    }
}

__global__ __launch_bounds__(1024) void finish_k(const float* __restrict__ diffc,
                                                 float* __restrict__ out) {
    __shared__ float red[16];
    int t = threadIdx.x, lane = t & 63, w = t >> 6;
    float v = diffc[t];
    v = wave_sum(v);
    if (lane == 0) red[w] = v;
    __syncthreads();
    if (w == 0) {
        float x = (lane < 16) ? red[lane] : 0.f;
        x = wave_sum(x);
        if (lane == 0) out[2112] = x * (1.f / 32.f);
    }
}

extern "C" void kernel_launch(void* const* d_in, const int* in_sizes, int n_in,
                              void* d_out, int out_size, void* d_ws, size_t ws_size,
                              hipStream_t stream) {
    const float* doc   = (const float*)d_in[0];   // [32,64,768]
    const float* sume  = (const float*)d_in[1];   // [32,32,768]
    const int*   ndoc  = (const int*)d_in[2];     // [32]
    const int*   nseg  = (const int*)d_in[3];     // [32]
    const float* agg   = (const float*)d_in[4];   // [32]
    const float* tinst = (const float*)d_in[5];   // [32,32]
    const float* W1    = (const float*)d_in[6];   // [1536,768]
    const float* b1    = (const float*)d_in[7];   // [768]
    const float* W2    = (const float*)d_in[8];   // [768,384]
    const float* b2    = (const float*)d_in[9];   // [384]
    const float* W3    = (const float*)d_in[10];  // [384,1]
    const float* b3    = (const float*)d_in[11];  // [1]
    float* out = (float*)d_out;
    char* ws = (char*)d_ws;

    float* hd    = (float*)(ws);                         // 2048*768 f32
    float* hs    = (float*)(ws + 6291456);               // 1024*768 f32
    float* rnd   = (float*)(ws + 9437184);               // 2048 f32
    float* rns   = (float*)(ws + 9445376);               // 1024 f32
    float* diffc = (float*)(ws + 9449472);               // 1024 f32
    unsigned short* docbf = (unsigned short*)(ws + 9453568);   // 2048*768 bf16
    unsigned short* sumbf = (unsigned short*)(ws + 12599296);  // 1024*768 bf16
    unsigned short* W1t   = (unsigned short*)(ws + 14172160);  // [768][1536] bf16
    unsigned short* W2t   = (unsigned short*)(ws + 16531456);  // [384][768] bf16

    prep_out<<<1, 1024, 0, stream>>>(agg, tinst, nseg, out);
    cvt_emb<<<2304, 256, 0, stream>>>(doc, sume, docbf, sumbf);
    tr_cvt<<<dim3(12, 24), 256, 0, stream>>>(W1, W1t, 1536, 768);
    tr_cvt<<<dim3(6, 12), 256, 0, stream>>>(W2, W2t, 768, 384);
    rnorm_k<<<768, 256, 0, stream>>>(doc, sume, rnd, rns);
    gemm1<<<dim3(6, 24), 256, 0, stream>>>(docbf, sumbf, W1t, hd, hs);
    score_mfma<<<512, 512, 0, stream>>>(hd, hs, b1, W2t, b2, W3, b3, ndoc, nseg, out);
    cos_diff<<<1024, 256, 0, stream>>>(doc, sume, ndoc, nseg, rnd, rns, out, diffc);
    finish_k<<<1, 1024, 0, stream>>>(diffc, out);
}

// Round 3
// 152.269 us; speedup vs baseline: 19.0490x; 1.1318x over previous
//
#include <hip/hip_runtime.h>
#include <hip/hip_bf16.h>
#include <math.h>

// Shapes: B=32, S=32, D=64, E=768
// out layout (floats): [0,32) agg | [32,1056) target_instance | [1056,2080) pred
//                      | [2080,2112) num_seg (as float) | [2112] cos_prior

typedef __bf16 bf16x8 __attribute__((ext_vector_type(8)));
typedef float f32x4 __attribute__((ext_vector_type(4)));

__device__ __forceinline__ unsigned short f2bf(float x) {
    unsigned int u = __float_as_uint(x);
    u = (u + 0x7fffu + ((u >> 16) & 1u)) >> 16;
    return (unsigned short)u;
}
// tanh-form GELU: x * sigmoid(1.5957691*x + 0.0713548*x^3); max abs err ~1e-3 vs erf form
__device__ __forceinline__ float gelu_fast(float x) {
    float u2 = x * fmaf(x * x, 0.0713548162726f, 1.5957691216057308f);
    return __fdividef(x, 1.0f + __expf(-u2));
}
__device__ __forceinline__ float sigmoid_fast(float x) {
    return __fdividef(1.0f, 1.0f + __expf(-x));
}
__device__ __forceinline__ float wave_sum(float v) {
    for (int o = 32; o; o >>= 1) v += __shfl_xor(v, o);
    return v;
}
__device__ __forceinline__ float wave_max(float v) {
    for (int o = 32; o; o >>= 1) v = fmaxf(v, __shfl_xor(v, o));
    return v;
}

// ---- prep: W1^T bf16, W2^T bf16, row rnorms, all in one launch ----
// blocks [0,288): W1 transpose ; [288,360): W2 transpose ; [360,1128): norms
__global__ __launch_bounds__(256) void prep_all(const float* __restrict__ W1,
                                                const float* __restrict__ W2,
                                                const float* __restrict__ doc,
                                                const float* __restrict__ sume,
                                                unsigned short* __restrict__ W1t,
                                                unsigned short* __restrict__ W2t,
                                                float* __restrict__ rnd,
                                                float* __restrict__ rns) {
    int id = blockIdx.x;
    int t = threadIdx.x;
    if (id < 360) {
        __shared__ float tile[64][65];
        const float* in; unsigned short* outp; int R, C, bx, by;
        if (id < 288) { in = W1; outp = W1t; R = 1536; C = 768; bx = id % 12; by = id / 12; }
        else { int i2 = id - 288; in = W2; outp = W2t; R = 768; C = 384; bx = i2 % 6; by = i2 / 6; }
        int r0 = by * 64, c0 = bx * 64;
        #pragma unroll
        for (int p = 0; p < 16; ++p) {
            int r = p * 4 + (t >> 6), c = t & 63;
            tile[r][c] = in[(r0 + r) * C + c0 + c];
        }
        __syncthreads();
        #pragma unroll
        for (int p = 0; p < 16; ++p) {
            int cc = p * 4 + (t >> 6), rr = t & 63;
            outp[(c0 + cc) * R + r0 + rr] = f2bf(tile[rr][cc]);
        }
    } else {
        int row = (id - 360) * 4 + (t >> 6);
        int lane = t & 63;
        const float* p; float* dst;
        if (row < 2048) { p = doc + row * 768; dst = rnd + row; }
        else            { p = sume + (row - 2048) * 768; dst = rns + row - 2048; }
        const float* pp = p + lane * 12;
        float4 a0 = *(const float4*)(pp);
        float4 a1 = *(const float4*)(pp + 4);
        float4 a2 = *(const float4*)(pp + 8);
        float s = a0.x*a0.x + a0.y*a0.y + a0.z*a0.z + a0.w*a0.w
                + a1.x*a1.x + a1.y*a1.y + a1.z*a1.z + a1.w*a1.w
                + a2.x*a2.x + a2.y*a2.y + a2.z*a2.z + a2.w*a2.w;
        s = wave_sum(s);
        if (lane == 0) *dst = rsqrtf(fmaxf(s, 1e-12f));
    }
}

// ---- stage-1 GEMM: [doc;sum] @ W1 -> hd/hs (fp32 out), conversion fused in staging ----
__global__ __launch_bounds__(256) void gemm1(const float* __restrict__ doc,
                                             const float* __restrict__ sume,
                                             const unsigned short* __restrict__ W1t,
                                             float* __restrict__ hd,
                                             float* __restrict__ hs) {
    __shared__ __align__(16) unsigned short Asw[128 * 64];
    __shared__ __align__(16) unsigned short Bsw[128 * 64];
    int t = threadIdx.x;
    int row0 = blockIdx.y * 128, col0 = blockIdx.x * 128;
    bool is_doc = row0 < 2048;
    const float* A = is_doc ? (doc + row0 * 768) : (sume + (row0 - 2048) * 768);
    int kbase = is_doc ? 0 : 768;
    float* O = is_doc ? (hd + row0 * 768) : (hs + (row0 - 2048) * 768);

    int l = t & 63, w = t >> 6;
    int wr = w >> 1, wc = w & 1;
    f32x4 acc[4][4];
    #pragma unroll
    for (int i = 0; i < 4; ++i)
        #pragma unroll
        for (int j = 0; j < 4; ++j) acc[i][j] = (f32x4)0.f;

    char* AswB = (char*)Asw;
    char* BswB = (char*)Bsw;
    for (int kt = 0; kt < 768; kt += 64) {
        __syncthreads();
        #pragma unroll
        for (int p = 0; p < 4; ++p) {
            int r = p * 32 + (t >> 3);
            int ko = (t & 7) * 8;
            float4 f0 = *(const float4*)(A + r * 768 + kt + ko);
            float4 f1 = *(const float4*)(A + r * 768 + kt + ko + 4);
            __hip_bfloat162 p0 = __float22bfloat162_rn(make_float2(f0.x, f0.y));
            __hip_bfloat162 p1 = __float22bfloat162_rn(make_float2(f0.z, f0.w));
            __hip_bfloat162 p2 = __float22bfloat162_rn(make_float2(f1.x, f1.y));
            __hip_bfloat162 p3 = __float22bfloat162_rn(make_float2(f1.z, f1.w));
            uint4 v = make_uint4(*(unsigned int*)&p0, *(unsigned int*)&p1,
                                 *(unsigned int*)&p2, *(unsigned int*)&p3);
            int byte = (r * 128 + ko * 2) ^ ((r & 7) << 4);
            *(uint4*)(AswB + byte) = v;
            bf16x8 bv = *(const bf16x8*)(W1t + (col0 + r) * 1536 + kbase + kt + ko);
            *(bf16x8*)(BswB + byte) = bv;
        }
        __syncthreads();
        #pragma unroll
        for (int ks = 0; ks < 2; ++ks) {
            int koff = (ks * 32 + (l >> 4) * 8) * 2;
            bf16x8 af[4], bfr[4];
            #pragma unroll
            for (int fr = 0; fr < 4; ++fr) {
                int r = wr * 64 + fr * 16 + (l & 15);
                af[fr] = *(const bf16x8*)(AswB + ((r * 128 + koff) ^ ((r & 7) << 4)));
            }
            #pragma unroll
            for (int fc = 0; fc < 4; ++fc) {
                int n = wc * 64 + fc * 16 + (l & 15);
                bfr[fc] = *(const bf16x8*)(BswB + ((n * 128 + koff) ^ ((n & 7) << 4)));
            }
            #pragma unroll
            for (int fr = 0; fr < 4; ++fr)
                #pragma unroll
                for (int fc = 0; fc < 4; ++fc)
                    acc[fr][fc] = __builtin_amdgcn_mfma_f32_16x16x32_bf16(af[fr], bfr[fc], acc[fr][fc], 0, 0, 0);
        }
    }
    #pragma unroll
    for (int fr = 0; fr < 4; ++fr)
        #pragma unroll
        for (int fc = 0; fc < 4; ++fc)
            #pragma unroll
            for (int j = 0; j < 4; ++j) {
                int r = wr * 64 + fr * 16 + (l >> 4) * 4 + j;
                int c = col0 + wc * 64 + fc * 16 + (l & 15);
                O[r * 768 + c] = acc[fr][fc][j];
            }
}

// ---- main fused kernel: double-buffered LDS, one barrier per K-tile ----
// block = (b, s-pair); 512 threads = 8 waves (2 row-waves x 4 col-waves)
__global__ __launch_bounds__(512, 2) void score_mfma(
    const float* __restrict__ hd, const float* __restrict__ hs,
    const float* __restrict__ b1, const unsigned short* __restrict__ W2t,
    const float* __restrict__ b2, const float* __restrict__ W3,
    const float* __restrict__ b3, const int* __restrict__ ndoc,
    const int* __restrict__ nseg, float* __restrict__ out)
{
    __shared__ __align__(16) unsigned short Asw[2][128 * 64];   // 2 x 16 KB
    __shared__ __align__(16) unsigned short Bsw[2][384 * 64];   // 2 x 48 KB
    __shared__ float spart[4][128];

    int t = threadIdx.x;
    // XCD-aware swizzle: 512 blocks, 64 per XCD -> blocks sharing b stay on one XCD
    int lb = (int)(blockIdx.x & 7) * 64 + (int)(blockIdx.x >> 3);
    int b = lb >> 4, sp = lb & 15;
    int l = t & 63, w = t >> 6;
    int wr = w >> 2, wc = w & 3;
    int nd = ndoc[b], ns = nseg[b];

    f32x4 acc[4][6];
    #pragma unroll
    for (int i = 0; i < 4; ++i)
        #pragma unroll
        for (int j = 0; j < 6; ++j) acc[i][j] = (f32x4)0.f;

    const float* hdB = hd + b * 64 * 768;
    const float* hs0 = hs + (b * 32 + sp * 2) * 768;
    const float* hs1 = hs0 + 768;

    int rbase = t >> 5;          // 0..15 (A-row sub-index)
    int k0 = (t & 31) * 2;       // 0..62 (A k-pair)
    int bn = t >> 3;             // 0..63 (B row sub-index)
    int bko = (t & 7) * 8;       // B k-offset

    float2 hv[8]; float2 hav, hbv; bf16x8 br[6];

#define STAGE_LOAD(KT)                                                        \
    {                                                                         \
        _Pragma("unroll")                                                     \
        for (int p = 0; p < 8; ++p) {                                         \
            int d = (p * 16 + rbase) & 63;                                    \
            hv[p] = *(const float2*)(hdB + d * 768 + (KT) + k0);              \
        }                                                                     \
        float2 bb = *(const float2*)(b1 + (KT) + k0);                         \
        hav = *(const float2*)(hs0 + (KT) + k0);                              \
        hbv = *(const float2*)(hs1 + (KT) + k0);                              \
        hav.x += bb.x; hav.y += bb.y; hbv.x += bb.x; hbv.y += bb.y;           \
        _Pragma("unroll")                                                     \
        for (int q = 0; q < 6; ++q)                                           \
            br[q] = *(const bf16x8*)(W2t + (q * 64 + bn) * 768 + (KT) + bko); \
    }

#define STAGE_STORE(BUF)                                                      \
    {                                                                         \
        char* AB = (char*)Asw[BUF];                                           \
        _Pragma("unroll")                                                     \
        for (int p = 0; p < 8; ++p) {                                         \
            float sx = (p < 4) ? hav.x : hbv.x;                               \
            float sy = (p < 4) ? hav.y : hbv.y;                               \
            float g0 = gelu_fast(hv[p].x + sx);                               \
            float g1 = gelu_fast(hv[p].y + sy);                               \
            __hip_bfloat162 pk = __float22bfloat162_rn(make_float2(g0, g1));  \
            int r = p * 16 + rbase;                                           \
            int byte = (r * 128 + k0 * 2) ^ ((r & 7) << 4);                   \
            *(unsigned int*)(AB + byte) = *(unsigned int*)&pk;                \
        }                                                                     \
        char* BB = (char*)Bsw[BUF];                                           \
        _Pragma("unroll")                                                     \
        for (int q = 0; q < 6; ++q) {                                         \
            int n = q * 64 + bn;                                              \
            int byte = (n * 128 + bko * 2) ^ ((n & 7) << 4);                  \
            *(bf16x8*)(BB + byte) = br[q];                                    \
        }                                                                     \
    }

    // prologue: stage tile 0 into buffer 0
    STAGE_LOAD(0)
    STAGE_STORE(0)

    #pragma unroll 1
    for (int i = 0; i < 12; ++i) {
        int cur = i & 1;
        bool more = (i < 11);
        if (more) STAGE_LOAD((i + 1) * 64)      // global loads in flight during MFMA
        __syncthreads();                        // buf[cur] staged; prev readers of buf[cur^1] done
        const char* AR = (const char*)Asw[cur];
        const char* BR = (const char*)Bsw[cur];
        #pragma unroll
        for (int ks = 0; ks < 2; ++ks) {
            int koff = (ks * 32 + (l >> 4) * 8) * 2;
            bf16x8 af[4], bfr[6];
            #pragma unroll
            for (int fr = 0; fr < 4; ++fr) {
                int r = wr * 64 + fr * 16 + (l & 15);
                af[fr] = *(const bf16x8*)(AR + ((r * 128 + koff) ^ ((r & 7) << 4)));
            }
            #pragma unroll
            for (int fc = 0; fc < 6; ++fc) {
                int n = wc * 96 + fc * 16 + (l & 15);
                bfr[fc] = *(const bf16x8*)(BR + ((n * 128 + koff) ^ ((n & 7) << 4)));
            }
            #pragma unroll
            for (int fr = 0; fr < 4; ++fr)
                #pragma unroll
                for (int fc = 0; fc < 6; ++fc)
                    acc[fr][fc] = __builtin_amdgcn_mfma_f32_16x16x32_bf16(af[fr], bfr[fc], acc[fr][fc], 0, 0, 0);
        }
        if (more) STAGE_STORE(cur ^ 1)          // gelu + LDS writes overlap MFMA drain
    }
#undef STAGE_LOAD
#undef STAGE_STORE

    // epilogue: h2 = gelu(acc + b2); score = sigmoid(h2 . W3 + b3); masked max over d
    float b2v[6], w3v[6];
    #pragma unroll
    for (int fc = 0; fc < 6; ++fc) {
        int col = wc * 96 + fc * 16 + (l & 15);
        b2v[fc] = b2[col];
        w3v[fc] = W3[col];
    }
    #pragma unroll
    for (int fr = 0; fr < 4; ++fr) {
        #pragma unroll
        for (int j = 0; j < 4; ++j) {
            float pr = 0.f;
            #pragma unroll
            for (int fc = 0; fc < 6; ++fc)
                pr += gelu_fast(acc[fr][fc][j] + b2v[fc]) * w3v[fc];
            pr += __shfl_xor(pr, 1);
            pr += __shfl_xor(pr, 2);
            pr += __shfl_xor(pr, 4);
            pr += __shfl_xor(pr, 8);
            if ((l & 15) == 0)
                spart[wc][wr * 64 + fr * 16 + (l >> 4) * 4 + j] = pr;
        }
    }
    __syncthreads();
    if (t < 128) {
        int row = t;
        float v = spart[0][row] + spart[1][row] + spart[2][row] + spart[3][row] + b3[0];
        float sc = sigmoid_fast(v);
        int d = row & 63, sl = row >> 6;
        float m = (d < nd) ? sc : 0.f;
        m = wave_max(m);
        if ((t & 63) == 0) {
            float segw = (ns > 10) ? 1.f : 100.f;
            out[1056 + b * 32 + sp * 2 + sl] = segw * m;
        }
    }
}

// ---- cosine branch: dscos[b,s] = max_{d<nd} (1 - cos(doc_d, sum_s))/2 ----
// 256 blocks = (b, s-quad); wave w handles s = (bid&7)*4 + w
__global__ __launch_bounds__(256) void cos_k(const float* __restrict__ doc,
                                             const float* __restrict__ sume,
                                             const int* __restrict__ ndoc,
                                             const float* __restrict__ rnd,
                                             const float* __restrict__ rns,
                                             float* __restrict__ dscos) {
    int t = threadIdx.x;
    int l = t & 63, w = t >> 6;
    int b = blockIdx.x >> 3;
    int s = (blockIdx.x & 7) * 4 + w;
    int bs = b * 32 + s;
    const float* sr = sume + bs * 768 + l * 12;
    float4 s0 = *(const float4*)(sr);
    float4 s1 = *(const float4*)(sr + 4);
    float4 s2 = *(const float4*)(sr + 8);
    int nd = ndoc[b];
    float rs = rns[bs];
    float mymax = 0.f;
    for (int d = 0; d < 64; ++d) {
        const float* dr = doc + (b * 64 + d) * 768 + l * 12;
        float4 a0 = *(const float4*)(dr);
        float4 a1 = *(const float4*)(dr + 4);
        float4 a2 = *(const float4*)(dr + 8);
        float dot = a0.x*s0.x + a0.y*s0.y + a0.z*s0.z + a0.w*s0.w
                  + a1.x*s1.x + a1.y*s1.y + a1.z*s1.z + a1.w*s1.w
                  + a2.x*s2.x + a2.y*s2.y + a2.z*s2.z + a2.w*s2.w;
        dot = wave_sum(dot);
        float val = (1.f - dot * rnd[b * 64 + d] * rs) * 0.5f;
        if (d < nd) mymax = fmaxf(mymax, val);
    }
    if (l == 0) dscos[bs] = mymax;
}

// ---- finish: passthrough outputs + cos_prior reduction ----
__global__ __launch_bounds__(1024) void finish_k(const float* __restrict__ agg,
                                                 const float* __restrict__ tinst,
                                                 const int* __restrict__ nseg,
                                                 const float* __restrict__ dscos,
                                                 float* __restrict__ out) {
    __shared__ float red[16];
    int t = threadIdx.x, lane = t & 63, w = t >> 6;
    int b = t >> 5, s = t & 31;
    int ns = nseg[b];
    out[32 + t] = (s < ns) ? tinst[t] : 1.0f;
    if (t < 32) {
        out[t] = agg[t];
        out[2080 + t] = (float)nseg[t];
    }
    float pred = out[1056 + t];
    float v = (s < ns) ? fabsf(dscos[t] - pred) / (float)ns : 0.f;
    v = wave_sum(v);
    if (lane == 0) red[w] = v;
    __syncthreads();
    if (w == 0) {
        float x = (lane < 16) ? red[lane] : 0.f;
        x = wave_sum(x);
        if (lane == 0) out[2112] = x * (1.f / 32.f);
    }
}

extern "C" void kernel_launch(void* const* d_in, const int* in_sizes, int n_in,
                              void* d_out, int out_size, void* d_ws, size_t ws_size,
                              hipStream_t stream) {
    const float* doc   = (const float*)d_in[0];   // [32,64,768]
    const float* sume  = (const float*)d_in[1];   // [32,32,768]
    const int*   ndoc  = (const int*)d_in[2];     // [32]
    const int*   nseg  = (const int*)d_in[3];     // [32]
    const float* agg   = (const float*)d_in[4];   // [32]
    const float* tinst = (const float*)d_in[5];   // [32,32]
    const float* W1    = (const float*)d_in[6];   // [1536,768]
    const float* b1    = (const float*)d_in[7];   // [768]
    const float* W2    = (const float*)d_in[8];   // [768,384]
    const float* b2    = (const float*)d_in[9];   // [384]
    const float* W3    = (const float*)d_in[10];  // [384,1]
    const float* b3    = (const float*)d_in[11];  // [1]
    float* out = (float*)d_out;
    char* ws = (char*)d_ws;

    float* hd    = (float*)(ws);                          // 2048*768 f32
    float* hs    = (float*)(ws + 6291456);                // 1024*768 f32
    float* rnd   = (float*)(ws + 9437184);                // 2048 f32
    float* rns   = (float*)(ws + 9445376);                // 1024 f32
    float* dscos = (float*)(ws + 9449472);                // 1024 f32
    unsigned short* W1t = (unsigned short*)(ws + 9453568);   // [768][1536] bf16
    unsigned short* W2t = (unsigned short*)(ws + 11812864);  // [384][768] bf16

    prep_all<<<1128, 256, 0, stream>>>(W1, W2, doc, sume, W1t, W2t, rnd, rns);
    gemm1<<<dim3(6, 24), 256, 0, stream>>>(doc, sume, W1t, hd, hs);
    score_mfma<<<512, 512, 0, stream>>>(hd, hs, b1, W2t, b2, W3, b3, ndoc, nseg, out);
    cos_k<<<256, 256, 0, stream>>>(doc, sume, ndoc, rnd, rns, dscos);
    finish_k<<<1, 1024, 0, stream>>>(agg, tinst, nseg, dscos, out);
}